// Round 5
// baseline (1068.403 us; speedup 1.0000x reference)
//
#include <hip/hip_runtime.h>
#include <hip/hip_bf16.h>

// Problem constants (fixed by the reference)
#define NN 50000
#define TT 16
#define FIN 16
#define GH 64     // GCN_H == GRU_H == 64
#define EH 128    // EDGE_H
#define EE 800000

typedef __attribute__((ext_vector_type(8))) short short8;
typedef __attribute__((ext_vector_type(4))) float f32x4;

// ---------------- ws layout (bytes) ----------------
#define WS_DINV  0          // N f32 (deg counts first, then dinv)
#define WS_SNORM 200704     // N f32
#define WS_FLOW  401408     // N f32
#define WS_WC    602112     // 192*16 f32 row-major Wc = Wih@gcnW
#define WS_WB    615168     // 192 f32   wb = Wih@gcnb
#define WS_EMB   616192     // N*64 f32
#define WS_AGGH  13416192   // N*T*16 ushort (25.6 MB), layout [n][t][16]
#define WS_AGGL  39016192   // N*T*16 ushort (25.6 MB)
// bf16 copies for k_edge overlay the aggh region (dead after k_gru3):
#define WS_EMBH  13416192   // N*64 ushort
#define WS_EMBL  19816192   // N*64 ushort
#define WS_EAH   26216192   // E*4 ushort
#define WS_EAL   32616192   // E*4 ushort
#define WS_OFF   64616192   // (N+1) i32
#define WS_CUR   64817152   // N i32
#define WS_ROWV  65017856   // EE i32
#define WS_NRMV  68217856   // EE f32 (dead after k_gather; tail reused below)
#define WS_WFH   68217856   // GRU weight frags hi [36][64][8] ushort (overlay nrmv)
#define WS_WFL   68254720   // GRU weight frags lo
#define WS_BA    68291584   // 256 f32 biasA
#define WS_BB    68292608   // 256 f32 biasB
#define WS_WPH   71417856   // 128*160 ushort (padded e1W hi)
#define WS_WPL   71458816   // 128*160 ushort (padded e1W lo)
#define WS_B1W2  71499776   // 128 float2 (e1b, e2W)

static __device__ inline ushort f2bf(float v) {
    __hip_bfloat16 b = __float2bfloat16(v);
    return *(ushort*)&b;
}
static __device__ inline float bf2f(ushort u) {
    __hip_bfloat16 b; *(ushort*)&b = u;
    return __bfloat162float(b);
}
static __device__ inline f32x4 mfma3(short8 ah, short8 al, short8 bh, short8 bl, f32x4 c) {
    c = __builtin_amdgcn_mfma_f32_16x16x32_bf16(ah, bh, c, 0, 0, 0);
    c = __builtin_amdgcn_mfma_f32_16x16x32_bf16(ah, bl, c, 0, 0, 0);
    c = __builtin_amdgcn_mfma_f32_16x16x32_bf16(al, bh, c, 0, 0, 0);
    return c;
}
static __device__ inline short8 ld8u(const ushort* p) {   // 8-B aligned LDS read
    short8 v;
    ((uint2*)&v)[0] = *(const uint2*)p;
    ((uint2*)&v)[1] = *(const uint2*)(p + 4);
    return v;
}

__global__ __launch_bounds__(256) void k_init(float* deg, float* flow) {
    int n = blockIdx.x * 256 + threadIdx.x;
    if (n < NN) { deg[n] = 1.0f; flow[n] = 0.0f; }
}

__global__ __launch_bounds__(256) void k_deg(const int* __restrict__ ei, float* deg) {
    int e = blockIdx.x * 256 + threadIdx.x;
    if (e < EE) atomicAdd(&deg[ei[EE + e]], 1.0f);
}

// Exclusive scan of cnt[n] = deg[n]-1 (incoming degree). Single block, 1024 thr.
__global__ __launch_bounds__(1024) void k_scan(const float* __restrict__ deg,
                                               int* __restrict__ off,
                                               int* __restrict__ cursor) {
    __shared__ int wsum[16];
    __shared__ int carryS;
    int tid = threadIdx.x, lane = tid & 63, wv = tid >> 6;
    if (tid == 0) carryS = 0;
    __syncthreads();
    for (int base = 0; base < NN; base += 4096) {
        int i0 = base + tid * 4;
        int v[4];
        int tot = 0;
        for (int q = 0; q < 4; q++) {
            int i = i0 + q;
            v[q] = (i < NN) ? (int)deg[i] - 1 : 0;
            tot += v[q];
        }
        int inc = tot;
        for (int d = 1; d < 64; d <<= 1) {
            int tpl = __shfl_up(inc, d, 64);
            if (lane >= d) inc += tpl;
        }
        if (lane == 63) wsum[wv] = inc;
        __syncthreads();
        int wexcl = 0;
        for (int k = 0; k < 16; k++) wexcl += (k < wv) ? wsum[k] : 0;
        int run = carryS + wexcl + inc - tot;
        __syncthreads();
        for (int q = 0; q < 4; q++) {
            int i = i0 + q;
            if (i < NN) { off[i] = run; cursor[i] = run; }
            run += v[q];
        }
        if (tid == 1023) carryS = run;
        __syncthreads();
    }
    if (threadIdx.x == 0) off[NN] = carryS;
}

__global__ __launch_bounds__(256) void k_dinv(float* deg_dinv) {
    int n = blockIdx.x * 256 + threadIdx.x;
    if (n < NN) deg_dinv[n] = rsqrtf(deg_dinv[n]);
}

// Fill CSR buckets: rowv/nrmv per destination.
__global__ __launch_bounds__(256) void k_fill(const int* __restrict__ ei,
                                              const float* __restrict__ dinv,
                                              int* __restrict__ cursor,
                                              int* __restrict__ rowv,
                                              float* __restrict__ nrmv) {
    int e = blockIdx.x * 256 + threadIdx.x;
    if (e >= EE) return;
    int r = ei[e], c = ei[EE + e];
    float nrm = dinv[r] * dinv[c];
    int p = atomicAdd(&cursor[c], 1);
    rowv[p] = r;
    nrmv[p] = nrm;
}

// Wc = W_ih @ gcn_W (192x16 row-major), wb = W_ih @ gcn_b
__global__ __launch_bounds__(256) void k_prep(const float* __restrict__ Wih,
                                              const float* __restrict__ gcnW,
                                              const float* __restrict__ gcnb,
                                              float* wc, float* wb) {
    int tid = blockIdx.x * 256 + threadIdx.x;
    if (tid < 3072) {
        int f = tid & 15, row = tid >> 4;
        float s = 0.f;
        for (int k = 0; k < 64; k++) s += Wih[row * 64 + k] * gcnW[k * 16 + f];
        wc[row * 16 + f] = s;
    } else if (tid < 3264) {
        int row = tid - 3072;
        float s = 0.f;
        for (int k = 0; k < 64; k++) s += Wih[row * 64 + k] * gcnb[k];
        wb[row] = s;
    }
}

// Packed-row value of the 256x96 GRU weight matrix:
// rows 0..127: [Whh | Wc | 0] (r,z); 128..191: [Whh_n | 0]; 192..255: [0 | Wc_n | 0]
static __device__ inline float pk_val(const float* whh, const float* wc, int row, int k) {
    if (row < 128)  return (k < 64) ? whh[row * 64 + k] : ((k < 80) ? wc[row * 16 + k - 64] : 0.f);
    if (row < 192)  return (k < 64) ? whh[row * 64 + k] : 0.f;
    return (k >= 64 && k < 80) ? wc[(row - 64) * 16 + k - 64] : 0.f;
}

// Build GRU weight MFMA fragments (hi/lo) in global, frag layout [cc=c*4+w][64][8],
// chunk list c: (i,ks) = (0,0)(0,1)(0,2)(1,0)(1,1)(1,2)(2,0)(2,1)(3,2). Plus biases.
__global__ __launch_bounds__(256) void k_prep3(const float* __restrict__ whh,
                                               const float* __restrict__ wc,
                                               const float* __restrict__ wb,
                                               const float* __restrict__ bih,
                                               const float* __restrict__ bhh,
                                               ushort* __restrict__ wfh,
                                               ushort* __restrict__ wfl,
                                               float* __restrict__ biasA,
                                               float* __restrict__ biasB) {
    const int ci[9] = {0, 0, 0, 1, 1, 1, 2, 2, 3};
    const int ck[9] = {0, 1, 2, 0, 1, 2, 0, 1, 2};
    int idx = blockIdx.x * 256 + threadIdx.x;
    if (idx < 2304) {
        int cc = idx >> 6, l = idx & 63;
        int c = cc >> 2, w = cc & 3;
        int lg = l >> 4, lr = l & 15;
        int row = ci[c] * 64 + w * 16 + lr;
        for (int e = 0; e < 8; e++) {
            int k = ck[c] * 32 + lg * 8 + e;
            float v = pk_val(whh, wc, row, k);
            uint b = __float_as_uint(v);
            uint hi = b & 0xFFFF0000u;
            float lo = v - __uint_as_float(hi);
            wfh[idx * 8 + e] = (ushort)(hi >> 16);
            wfl[idx * 8 + e] = (ushort)(__float_as_uint(lo) >> 16);
        }
    } else if (idx < 2560) {
        int row = idx - 2304;
        int g = (row < 192) ? row : row - 64;
        float ba, bb;
        if (row < 128)      { ba = bih[row] + bhh[row]; bb = wb[row]; }
        else if (row < 192) { ba = bhh[row];            bb = 0.f; }
        else                { ba = bih[g];              bb = wb[g]; }
        biasA[row] = ba;
        biasB[row] = bb;
    }
}

// Padded bf16 hi/lo copy of e1W ([128][160], k>=132 zero) + (e1b,e2W) float2 table.
__global__ __launch_bounds__(256) void k_prepw(const float* __restrict__ e1W,
                                               const float* __restrict__ e1b,
                                               const float* __restrict__ e2W,
                                               ushort* __restrict__ wph,
                                               ushort* __restrict__ wpl,
                                               float2* __restrict__ b1w2) {
    int idx = blockIdx.x * 256 + threadIdx.x;
    if (idx < 20480) {
        int h = idx / 160, k = idx - h * 160;
        float v = (k < 132) ? e1W[h * 132 + k] : 0.f;
        ushort hb = f2bf(v);
        wph[idx] = hb;
        wpl[idx] = f2bf(v - bf2f(hb));
    } else if (idx < 20608) {
        int h = idx - 20480;
        b1w2[h] = make_float2(e1b[h], e2W[h]);
    }
}

// Gather, t-blocked for L2 locality: grid (N/4, T); wave = one (node,t).
// Lanes: f = l&15 (feature), es = l>>4 (edge slot). Also computes snorm (t==0).
__global__ __launch_bounds__(256) void k_gather(const float* __restrict__ x,
                                                const float* __restrict__ dinv,
                                                const int* __restrict__ off,
                                                const int* __restrict__ rowv,
                                                const float* __restrict__ nrmv,
                                                ushort* __restrict__ aggh,
                                                ushort* __restrict__ aggl,
                                                float* __restrict__ snorm) {
    int wv = threadIdx.x >> 6, l = threadIdx.x & 63;
    int f = l & 15, es = l >> 4;
    int n = blockIdx.x * 4 + wv;
    int t = blockIdx.y;
    int s = off[n], e = off[n + 1];
    const float* xt = x + (size_t)t * NN * 16;
    float acc = 0.f, sacc = 0.f;
    for (int i = s + es; i < e; i += 4) {
        int r = rowv[i];
        float nr = nrmv[i];
        acc += nr * xt[(size_t)r * 16 + f];
        if (f == 0) sacc += nr;
    }
    acc += __shfl_xor(acc, 16, 64);
    acc += __shfl_xor(acc, 32, 64);
    float d = dinv[n], d2 = d * d;
    acc += d2 * xt[(size_t)n * 16 + f];
    if (t == 0) {
        sacc += __shfl_xor(sacc, 16, 64);
        sacc += __shfl_xor(sacc, 32, 64);
        if (l == 0) snorm[n] = sacc + d2;
    }
    if (l < 16) {
        uint b = __float_as_uint(acc);
        uint hi = b & 0xFFFF0000u;
        float lo = acc - __uint_as_float(hi);
        size_t ao = ((size_t)n * 16 + t) * 16 + f;
        aggh[ao] = (ushort)(hi >> 16);
        aggl[ao] = (ushort)(__float_as_uint(lo) >> 16);
    }
}

// MFMA GRU v3: block = 64 nodes, 4 waves. Wave w owns j-slice j = w*16+lr of all
// 4 gate blocks -> in-register elementwise update (round-4 validated orientation).
// W-hi frags staged in LDS (linear frag layout, conflict-free b128); W-lo streamed
// from L2 per t (short live range); h single-buffered in LDS, 2 barriers/t.
__global__ __launch_bounds__(256) void k_gru3(const ushort* __restrict__ aggh,
                                              const ushort* __restrict__ aggl,
                                              const float* __restrict__ snorm,
                                              const ushort* __restrict__ wfh,
                                              const ushort* __restrict__ wfl,
                                              const float* __restrict__ biasA,
                                              const float* __restrict__ biasB,
                                              float* __restrict__ emb) {
    __shared__ ushort sWh[36 * 64 * 8];   // 36864 B, frag layout [cc][64][8]
    __shared__ ushort sHi[64][68];        // 8704 B
    __shared__ ushort sLo[64][68];        // 8704 B
    int tid = threadIdx.x;
    int w = tid >> 6, l = tid & 63;
    int lg = l >> 4, lr = l & 15;
    int base = blockIdx.x * 64;
    int j = w * 16 + lr;

    for (int i = tid; i < 2304; i += 256)
        ((uint4*)sWh)[i] = ((const uint4*)wfh)[i];
    for (int i = tid; i < 64 * 68; i += 256) {
        ((ushort*)sHi)[i] = 0;
        ((ushort*)sLo)[i] = 0;
    }

    float bA[4], bB[4];
    #pragma unroll
    for (int i = 0; i < 4; i++) {
        bA[i] = biasA[i * 64 + j];
        bB[i] = biasB[i * 64 + j];
    }
    float snr[4][4], hold[4][4];
    #pragma unroll
    for (int tl = 0; tl < 4; tl++)
        #pragma unroll
        for (int q = 0; q < 4; q++) {
            int n = base + tl * 16 + lg * 4 + q;
            snr[tl][q] = snorm[min(n, NN - 1)];
            hold[tl][q] = 0.f;
        }
    int nA[4];
    #pragma unroll
    for (int tl = 0; tl < 4; tl++) nA[tl] = min(base + tl * 16 + lr, NN - 1);

    __syncthreads();

    #pragma unroll 1
    for (int t = 0; t < TT; t++) {
        // Per-t weight fragments: hi from LDS, lo from L2 (short live ranges).
        short8 bh[9], bl[9];
        #pragma unroll
        for (int c = 0; c < 9; c++) {
            int offs = ((c * 4 + w) * 64 + l) * 8;
            bh[c] = *(const short8*)(sWh + offs);
            bl[c] = *(const short8*)(wfl + offs);
        }
        f32x4 acc[4][4];
        #pragma unroll
        for (int i = 0; i < 4; i++)
            #pragma unroll
            for (int tl = 0; tl < 4; tl++)
                #pragma unroll
                for (int q = 0; q < 4; q++)
                    acc[i][tl][q] = bA[i] + snr[tl][q] * bB[i];

        #pragma unroll
        for (int tl = 0; tl < 4; tl++) {
            int nd = tl * 16 + lr;
            const ushort* ph = &sHi[nd][lg * 8];
            const ushort* pl = &sLo[nd][lg * 8];
            short8 Ah0 = ld8u(ph);
            short8 Ah1 = ld8u(ph + 32);
            short8 Al0 = ld8u(pl);
            short8 Al1 = ld8u(pl + 32);
            short8 Ah2 = {0,0,0,0,0,0,0,0};
            short8 Al2 = {0,0,0,0,0,0,0,0};
            if (lg < 2) {
                size_t ao = (size_t)nA[tl] * 256 + t * 16 + lg * 8;
                Ah2 = *(const short8*)(aggh + ao);
                Al2 = *(const short8*)(aggl + ao);
            }
            acc[0][tl] = mfma3(Ah0, Al0, bh[0], bl[0], acc[0][tl]);
            acc[0][tl] = mfma3(Ah1, Al1, bh[1], bl[1], acc[0][tl]);
            acc[0][tl] = mfma3(Ah2, Al2, bh[2], bl[2], acc[0][tl]);
            acc[1][tl] = mfma3(Ah0, Al0, bh[3], bl[3], acc[1][tl]);
            acc[1][tl] = mfma3(Ah1, Al1, bh[4], bl[4], acc[1][tl]);
            acc[1][tl] = mfma3(Ah2, Al2, bh[5], bl[5], acc[1][tl]);
            acc[2][tl] = mfma3(Ah0, Al0, bh[6], bl[6], acc[2][tl]);
            acc[2][tl] = mfma3(Ah1, Al1, bh[7], bl[7], acc[2][tl]);
            acc[3][tl] = mfma3(Ah2, Al2, bh[8], bl[8], acc[3][tl]);
        }
        __syncthreads();   // all h reads of this t done before overwriting

        #pragma unroll
        for (int tl = 0; tl < 4; tl++)
            #pragma unroll
            for (int q = 0; q < 4; q++) {
                float r = 1.f / (1.f + __expf(-acc[0][tl][q]));
                float z = 1.f / (1.f + __expf(-acc[1][tl][q]));
                float a = acc[3][tl][q] + r * acc[2][tl][q];
                a = fminf(fmaxf(a, -15.f), 15.f);
                float e2 = __expf(2.f * a);
                float nnv = (e2 - 1.f) / (e2 + 1.f);
                float hv = (1.f - z) * nnv + z * hold[tl][q];
                hold[tl][q] = hv;
                uint b = __float_as_uint(hv);
                uint hi = b & 0xFFFF0000u;
                float lo = hv - __uint_as_float(hi);
                int nd = tl * 16 + lg * 4 + q;
                sHi[nd][j] = (ushort)(hi >> 16);
                sLo[nd][j] = (ushort)(__float_as_uint(lo) >> 16);
            }
        __syncthreads();   // h_{t+1} visible before next t's reads
    }

    #pragma unroll
    for (int tl = 0; tl < 4; tl++)
        #pragma unroll
        for (int q = 0; q < 4; q++) {
            int n = base + tl * 16 + lg * 4 + q;
            if (n < NN) emb[(size_t)n * 64 + j] = hold[tl][q];
        }
}

// Convert emb (N*64 = 3.2M) and ea (E*4 = 3.2M) to bf16 hi/lo.
__global__ __launch_bounds__(256) void k_cvt(const float* __restrict__ emb,
                                             const float* __restrict__ ea,
                                             ushort* __restrict__ embh,
                                             ushort* __restrict__ embl,
                                             ushort* __restrict__ eah,
                                             ushort* __restrict__ eal) {
    int i = blockIdx.x * 256 + threadIdx.x;
    if (i >= 3200000) return;
    float v = emb[i];
    ushort hb = f2bf(v);
    embh[i] = hb;
    embl[i] = f2bf(v - bf2f(hb));
    float u = ea[i];
    ushort hb2 = f2bf(u);
    eah[i] = hb2;
    eal[i] = f2bf(u - bf2f(hb2));
}

// Edge MLP via MFMA, bf16 hi/lo split (3 passes = f32-accurate).
__global__ __launch_bounds__(256) void k_edge(const ushort* __restrict__ embh,
                                              const ushort* __restrict__ embl,
                                              const ushort* __restrict__ eah,
                                              const ushort* __restrict__ eal,
                                              const ushort* __restrict__ wph,
                                              const ushort* __restrict__ wpl,
                                              const float2* __restrict__ b1w2,
                                              const int* __restrict__ ei,
                                              const float* __restrict__ e2b,
                                              float* __restrict__ pred_edge,
                                              float* __restrict__ flow) {
    int w = threadIdx.x >> 6, l = threadIdx.x & 63;
    int lg = l >> 4, lr = l & 15;
    int ebase = (blockIdx.x * 4 + w) * 32;

    short8 Ah[2][5], Al[2][5];
    for (int s = 0; s < 2; s++) {
        int e = ebase + s * 16 + lr;
        int r = ei[e], c = ei[EE + e];
        for (int ks = 0; ks < 4; ks++) {
            int src = (ks < 2) ? r : c;
            int kk = (ks & 1) * 32 + lg * 8;
            Ah[s][ks] = *(const short8*)(embh + (size_t)src * 64 + kk);
            Al[s][ks] = *(const short8*)(embl + (size_t)src * 64 + kk);
        }
        short8 zh = {0, 0, 0, 0, 0, 0, 0, 0};
        short8 zl = {0, 0, 0, 0, 0, 0, 0, 0};
        if (lg == 0) {
            const uint* ph4 = (const uint*)(eah + (size_t)e * 4);
            const uint* pl4 = (const uint*)(eal + (size_t)e * 4);
            ((uint*)&zh)[0] = ph4[0]; ((uint*)&zh)[1] = ph4[1];
            ((uint*)&zl)[0] = pl4[0]; ((uint*)&zl)[1] = pl4[1];
        }
        Ah[s][4] = zh;
        Al[s][4] = zl;
    }

    float esum[2][4];
    for (int s = 0; s < 2; s++)
        for (int q = 0; q < 4; q++) esum[s][q] = 0.f;

    for (int nt = 0; nt < 8; nt++) {
        int n0 = nt * 16;
        f32x4 acc[2] = {{0.f, 0.f, 0.f, 0.f}, {0.f, 0.f, 0.f, 0.f}};
        const ushort* wbh = wph + (size_t)(n0 + lr) * 160 + lg * 8;
        const ushort* wbl = wpl + (size_t)(n0 + lr) * 160 + lg * 8;
        for (int ks = 0; ks < 5; ks++) {
            short8 bh = *(const short8*)(wbh + ks * 32);
            short8 bl = *(const short8*)(wbl + ks * 32);
            for (int s = 0; s < 2; s++) {
                acc[s] = __builtin_amdgcn_mfma_f32_16x16x32_bf16(Ah[s][ks], bh, acc[s], 0, 0, 0);
                acc[s] = __builtin_amdgcn_mfma_f32_16x16x32_bf16(Ah[s][ks], bl, acc[s], 0, 0, 0);
                acc[s] = __builtin_amdgcn_mfma_f32_16x16x32_bf16(Al[s][ks], bh, acc[s], 0, 0, 0);
            }
        }
        float2 bw = b1w2[n0 + lr];
        for (int s = 0; s < 2; s++)
            for (int q = 0; q < 4; q++)
                esum[s][q] += fmaxf(acc[s][q] + bw.x, 0.f) * bw.y;
    }
    for (int m = 1; m < 16; m <<= 1)
        for (int s = 0; s < 2; s++)
            for (int q = 0; q < 4; q++)
                esum[s][q] += __shfl_xor(esum[s][q], m, 64);
    if (lr == 0) {
        float eb = e2b[0];
        for (int s = 0; s < 2; s++)
            for (int q = 0; q < 4; q++) {
                int e = ebase + s * 16 + lg * 4 + q;
                float pv = esum[s][q] + eb;
                pred_edge[e] = pv;
                atomicAdd(&flow[ei[EE + e]], pv);
            }
    }
}

// Node MLP: one wave per node, lane j = hidden unit j
__global__ __launch_bounds__(256) void k_node(const float* __restrict__ emb,
                                              const float* __restrict__ flow,
                                              const float* __restrict__ p1W,
                                              const float* __restrict__ p1b,
                                              const float* __restrict__ p2W,
                                              const float* __restrict__ p2b,
                                              float* __restrict__ out) {
    int w = threadIdx.x >> 6, j = threadIdx.x & 63;
    int n = blockIdx.x * 4 + w;
    if (n >= NN) return;
    const float* wrow = p1W + j * 65;
    const float* ev = emb + (size_t)n * 64;
    float acc = p1b[j];
    for (int f = 0; f < 64; f++) acc += wrow[f] * ev[f];
    acc += wrow[64] * flow[n];
    float val = p2W[j] * fmaxf(acc, 0.f);
    for (int m = 1; m < 64; m <<= 1) val += __shfl_xor(val, m, 64);
    if (j == 0) out[n] = val + p2b[0];
}

extern "C" void kernel_launch(void* const* d_in, const int* in_sizes, int n_in,
                              void* d_out, int out_size, void* d_ws, size_t ws_size,
                              hipStream_t stream) {
    (void)in_sizes; (void)n_in; (void)out_size; (void)ws_size;
    const float* x    = (const float*)d_in[0];
    const float* ea   = (const float*)d_in[1];
    const float* gcnW = (const float*)d_in[2];
    const float* gcnb = (const float*)d_in[3];
    const float* Wih  = (const float*)d_in[4];
    const float* Whh  = (const float*)d_in[5];
    const float* bih  = (const float*)d_in[6];
    const float* bhh  = (const float*)d_in[7];
    const float* e1W  = (const float*)d_in[8];
    const float* e1b  = (const float*)d_in[9];
    const float* e2W  = (const float*)d_in[10];
    const float* e2b  = (const float*)d_in[11];
    const float* p1W  = (const float*)d_in[12];
    const float* p1b  = (const float*)d_in[13];
    const float* p2W  = (const float*)d_in[14];
    const float* p2b  = (const float*)d_in[15];
    const int*   ei   = (const int*)d_in[16];

    char* ws = (char*)d_ws;
    float*  dinv  = (float*)(ws + WS_DINV);
    float*  snorm = (float*)(ws + WS_SNORM);
    float*  flow  = (float*)(ws + WS_FLOW);
    float*  wc    = (float*)(ws + WS_WC);
    float*  wb    = (float*)(ws + WS_WB);
    float*  emb   = (float*)(ws + WS_EMB);
    ushort* aggh  = (ushort*)(ws + WS_AGGH);
    ushort* aggl  = (ushort*)(ws + WS_AGGL);
    ushort* embh  = (ushort*)(ws + WS_EMBH);
    ushort* embl  = (ushort*)(ws + WS_EMBL);
    ushort* eah   = (ushort*)(ws + WS_EAH);
    ushort* eal   = (ushort*)(ws + WS_EAL);
    int*    off   = (int*)(ws + WS_OFF);
    int*    cur   = (int*)(ws + WS_CUR);
    int*    rowv  = (int*)(ws + WS_ROWV);
    float*  nrmv  = (float*)(ws + WS_NRMV);
    ushort* wfh   = (ushort*)(ws + WS_WFH);
    ushort* wfl   = (ushort*)(ws + WS_WFL);
    float*  biasA = (float*)(ws + WS_BA);
    float*  biasB = (float*)(ws + WS_BB);
    ushort* wph   = (ushort*)(ws + WS_WPH);
    ushort* wpl   = (ushort*)(ws + WS_WPL);
    float2* b1w2  = (float2*)(ws + WS_B1W2);

    float* pred_node = (float*)d_out;
    float* pred_edge = (float*)d_out + NN;

    k_init<<<(NN + 255) / 256, 256, 0, stream>>>(dinv, flow);
    k_deg<<<(EE + 255) / 256, 256, 0, stream>>>(ei, dinv);
    k_scan<<<1, 1024, 0, stream>>>(dinv, off, cur);
    k_dinv<<<(NN + 255) / 256, 256, 0, stream>>>(dinv);
    k_prep<<<13, 256, 0, stream>>>(Wih, gcnW, gcnb, wc, wb);
    k_prepw<<<81, 256, 0, stream>>>(e1W, e1b, e2W, wph, wpl, b1w2);
    k_fill<<<(EE + 255) / 256, 256, 0, stream>>>(ei, dinv, cur, rowv, nrmv);
    k_gather<<<dim3(NN / 4, TT), 256, 0, stream>>>(x, dinv, off, rowv, nrmv, aggh, aggl, snorm);
    k_prep3<<<10, 256, 0, stream>>>(Whh, wc, wb, bih, bhh, wfh, wfl, biasA, biasB);  // after k_gather: overlays nrmv
    k_gru3<<<(NN + 63) / 64, 256, 0, stream>>>(aggh, aggl, snorm, wfh, wfl, biasA, biasB, emb);
    k_cvt<<<(3200000 + 255) / 256, 256, 0, stream>>>(emb, ea, embh, embl, eah, eal);
    k_edge<<<EE / 128, 256, 0, stream>>>(embh, embl, eah, eal, wph, wpl, b1w2, ei, e2b, pred_edge, flow);
    k_node<<<(NN + 3) / 4, 256, 0, stream>>>(emb, flow, p1W, p1b, p2W, p2b, pred_node);
}

// Round 6
// 875.803 us; speedup vs baseline: 1.2199x; 1.2199x over previous
//
#include <hip/hip_runtime.h>
#include <hip/hip_bf16.h>

// Problem constants (fixed by the reference)
#define NN 50000
#define TT 16
#define EE 800000

typedef __attribute__((ext_vector_type(8))) short short8;
typedef __attribute__((ext_vector_type(4))) float f32x4;

// ---------------- ws layout (bytes) ----------------
#define WS_DINV   0          // N f32 (deg counts, then dinv)
#define WS_SNORM  200704     // N f32
#define WS_WC     401408     // 192*16 f32
#define WS_WB     413696     // 192 f32
#define WS_W1EA   414464     // 128*4 f32 (e1W edge-attr cols)
#define WS_B1W2   416512     // 128 float2 (e1b, e2W)
#define WS_BA     417536     // 256 f32 GRU biasA
#define WS_BB     418560     // 256 f32 GRU biasB
#define WS_EMB    419840     // N*64 f32
#define WS_OFF    13219840   // (N+1) i32
#define WS_CUR    13420032   // N i32
#define WS_ROWV   13620224   // EE i32  (CSR src)
#define WS_COLV   16820224   // EE i32  (CSR dst)
#define WS_EIDV   20020224   // EE i32  (CSR -> original edge id)
#define WS_NRMV   23220224   // EE f32
#define WS_WFH    26420224   // GRU weight frags hi [36][64][8] ushort
#define WS_WFL    26457088   // GRU weight frags lo
#define WS_WEH    26493952   // edge W frags hi [8][4][64][8] ushort (32KB)
#define WS_WEL    26526720   // edge W frags lo (32KB)
#define WS_AGGH   26560000   // N*T*16 ushort (25.6MB) [n][t][16]
#define WS_AGGL   52160000   // N*T*16 ushort (25.6MB)
// overlays inside AGGH region (dead after k_gru3):
#define WS_PREDV  26560000   // EE f32 (CSR-ordered edge preds)
#define WS_EMBH   29760000   // N*64 ushort
#define WS_EMBL   36160000   // N*64 ushort
// high water ~77.8 MB

static __device__ inline ushort f2bf(float v) {
    __hip_bfloat16 b = __float2bfloat16(v);
    return *(ushort*)&b;
}
static __device__ inline float bf2f(ushort u) {
    __hip_bfloat16 b; *(ushort*)&b = u;
    return __bfloat162float(b);
}
static __device__ inline f32x4 mfma3(short8 ah, short8 al, short8 bh, short8 bl, f32x4 c) {
    c = __builtin_amdgcn_mfma_f32_16x16x32_bf16(ah, bh, c, 0, 0, 0);
    c = __builtin_amdgcn_mfma_f32_16x16x32_bf16(ah, bl, c, 0, 0, 0);
    c = __builtin_amdgcn_mfma_f32_16x16x32_bf16(al, bh, c, 0, 0, 0);
    return c;
}
static __device__ inline short8 ld8u(const ushort* p) {   // 8-B aligned LDS read
    short8 v;
    ((uint2*)&v)[0] = *(const uint2*)p;
    ((uint2*)&v)[1] = *(const uint2*)(p + 4);
    return v;
}

__global__ __launch_bounds__(256) void k_init(float* deg) {
    int n = blockIdx.x * 256 + threadIdx.x;
    if (n < NN) deg[n] = 1.0f;
}

__global__ __launch_bounds__(256) void k_deg(const int* __restrict__ ei, float* deg) {
    int e = blockIdx.x * 256 + threadIdx.x;
    if (e < EE) atomicAdd(&deg[ei[EE + e]], 1.0f);
}

// Exclusive scan of cnt[n] = deg[n]-1 (incoming degree). Single block, 1024 thr.
__global__ __launch_bounds__(1024) void k_scan(const float* __restrict__ deg,
                                               int* __restrict__ off,
                                               int* __restrict__ cursor) {
    __shared__ int wsum[16];
    __shared__ int carryS;
    int tid = threadIdx.x, lane = tid & 63, wv = tid >> 6;
    if (tid == 0) carryS = 0;
    __syncthreads();
    for (int base = 0; base < NN; base += 4096) {
        int i0 = base + tid * 4;
        int v[4];
        int tot = 0;
        for (int q = 0; q < 4; q++) {
            int i = i0 + q;
            v[q] = (i < NN) ? (int)deg[i] - 1 : 0;
            tot += v[q];
        }
        int inc = tot;
        for (int d = 1; d < 64; d <<= 1) {
            int tpl = __shfl_up(inc, d, 64);
            if (lane >= d) inc += tpl;
        }
        if (lane == 63) wsum[wv] = inc;
        __syncthreads();
        int wexcl = 0;
        for (int k = 0; k < 16; k++) wexcl += (k < wv) ? wsum[k] : 0;
        int run = carryS + wexcl + inc - tot;
        __syncthreads();
        for (int q = 0; q < 4; q++) {
            int i = i0 + q;
            if (i < NN) { off[i] = run; cursor[i] = run; }
            run += v[q];
        }
        if (tid == 1023) carryS = run;
        __syncthreads();
    }
    if (threadIdx.x == 0) off[NN] = carryS;
}

__global__ __launch_bounds__(256) void k_dinv(float* deg_dinv) {
    int n = blockIdx.x * 256 + threadIdx.x;
    if (n < NN) deg_dinv[n] = rsqrtf(deg_dinv[n]);
}

// Fill CSR buckets: rowv/colv/eidv/nrmv per destination.
__global__ __launch_bounds__(256) void k_fill(const int* __restrict__ ei,
                                              const float* __restrict__ dinv,
                                              int* __restrict__ cursor,
                                              int* __restrict__ rowv,
                                              int* __restrict__ colv,
                                              int* __restrict__ eidv,
                                              float* __restrict__ nrmv) {
    int e = blockIdx.x * 256 + threadIdx.x;
    if (e >= EE) return;
    int r = ei[e], c = ei[EE + e];
    float nrm = dinv[r] * dinv[c];
    int p = atomicAdd(&cursor[c], 1);
    rowv[p] = r;
    colv[p] = c;
    eidv[p] = e;
    nrmv[p] = nrm;
}

// Wc = W_ih @ gcn_W (192x16 row-major), wb = W_ih @ gcn_b
__global__ __launch_bounds__(256) void k_prep(const float* __restrict__ Wih,
                                              const float* __restrict__ gcnW,
                                              const float* __restrict__ gcnb,
                                              float* wc, float* wb) {
    int tid = blockIdx.x * 256 + threadIdx.x;
    if (tid < 3072) {
        int f = tid & 15, row = tid >> 4;
        float s = 0.f;
        for (int k = 0; k < 64; k++) s += Wih[row * 64 + k] * gcnW[k * 16 + f];
        wc[row * 16 + f] = s;
    } else if (tid < 3264) {
        int row = tid - 3072;
        float s = 0.f;
        for (int k = 0; k < 64; k++) s += Wih[row * 64 + k] * gcnb[k];
        wb[row] = s;
    }
}

// Packed-row value of the 256x96 GRU weight matrix:
// rows 0..127: [Whh | Wc | 0] (r,z); 128..191: [Whh_n | 0]; 192..255: [0 | Wc_n | 0]
static __device__ inline float pk_val(const float* whh, const float* wc, int row, int k) {
    if (row < 128)  return (k < 64) ? whh[row * 64 + k] : ((k < 80) ? wc[row * 16 + k - 64] : 0.f);
    if (row < 192)  return (k < 64) ? whh[row * 64 + k] : 0.f;
    return (k >= 64 && k < 80) ? wc[(row - 64) * 16 + k - 64] : 0.f;
}

// Build GRU weight MFMA fragments (hi/lo), frag layout [cc=c*4+w][64][8] + biases.
__global__ __launch_bounds__(256) void k_prep3(const float* __restrict__ whh,
                                               const float* __restrict__ wc,
                                               const float* __restrict__ wb,
                                               const float* __restrict__ bih,
                                               const float* __restrict__ bhh,
                                               ushort* __restrict__ wfh,
                                               ushort* __restrict__ wfl,
                                               float* __restrict__ biasA,
                                               float* __restrict__ biasB) {
    const int ci[9] = {0, 0, 0, 1, 1, 1, 2, 2, 3};
    const int ck[9] = {0, 1, 2, 0, 1, 2, 0, 1, 2};
    int idx = blockIdx.x * 256 + threadIdx.x;
    if (idx < 2304) {
        int cc = idx >> 6, l = idx & 63;
        int c = cc >> 2, w = cc & 3;
        int lg = l >> 4, lr = l & 15;
        int row = ci[c] * 64 + w * 16 + lr;
        for (int e = 0; e < 8; e++) {
            int k = ck[c] * 32 + lg * 8 + e;
            float v = pk_val(whh, wc, row, k);
            uint b = __float_as_uint(v);
            uint hi = b & 0xFFFF0000u;
            float lo = v - __uint_as_float(hi);
            wfh[idx * 8 + e] = (ushort)(hi >> 16);
            wfl[idx * 8 + e] = (ushort)(__float_as_uint(lo) >> 16);
        }
    } else if (idx < 2560) {
        int row = idx - 2304;
        int g = (row < 192) ? row : row - 64;
        float ba, bb;
        if (row < 128)      { ba = bih[row] + bhh[row]; bb = wb[row]; }
        else if (row < 192) { ba = bhh[row];            bb = 0.f; }
        else                { ba = bih[g];              bb = wb[g]; }
        biasA[row] = ba;
        biasB[row] = bb;
    }
}

// Edge-MLP weight frags in MFMA frag layout [nt][ks][l][8] (hi/lo), K=128 only;
// + w1ea (edge-attr cols of e1W) + (e1b,e2W) table.
__global__ __launch_bounds__(256) void k_prepw(const float* __restrict__ e1W,
                                               const float* __restrict__ e1b,
                                               const float* __restrict__ e2W,
                                               ushort* __restrict__ weh,
                                               ushort* __restrict__ wel,
                                               float* __restrict__ w1ea,
                                               float2* __restrict__ b1w2) {
    int idx = blockIdx.x * 256 + threadIdx.x;
    if (idx < 16384) {
        int cc = idx >> 9;            // (nt*4+ks)
        int li = (idx >> 3) & 63;
        int e  = idx & 7;
        int nt = cc >> 2, ks = cc & 3;
        int row = nt * 16 + (li & 15);
        int k   = ks * 32 + (li >> 4) * 8 + e;
        float v = e1W[row * 132 + k];
        uint b = __float_as_uint(v);
        uint hi = b & 0xFFFF0000u;
        float lo = v - __uint_as_float(hi);
        weh[idx] = (ushort)(hi >> 16);
        wel[idx] = (ushort)(__float_as_uint(lo) >> 16);
    } else if (idx < 16896) {
        int t = idx - 16384;
        int h = t >> 2, j = t & 3;
        w1ea[t] = e1W[h * 132 + 128 + j];
    } else if (idx < 17024) {
        int h = idx - 16896;
        b1w2[h] = make_float2(e1b[h], e2W[h]);
    }
}

// Gather (round-4 structure, validated 245us): one wave per node;
// lane = (t = lane>>2, f4 = lane&3). Unroll-4 edges; fused snorm.
__global__ __launch_bounds__(256) void k_gather(const float* __restrict__ x,
                                                const float* __restrict__ dinv,
                                                const int* __restrict__ off,
                                                const int* __restrict__ rowv,
                                                const float* __restrict__ nrmv,
                                                ushort* __restrict__ aggh,
                                                ushort* __restrict__ aggl,
                                                float* __restrict__ snorm) {
    int wv = threadIdx.x >> 6, lane = threadIdx.x & 63;
    int n = blockIdx.x * 4 + wv;
    if (n >= NN) return;
    int t = lane >> 2, f4 = lane & 3;
    int s = off[n], e = off[n + 1];
    size_t toff = ((size_t)t * NN) * 16 + f4 * 4;
    float4 acc = make_float4(0.f, 0.f, 0.f, 0.f);
    float sacc = 0.f;
    int i = s;
    for (; i + 3 < e; i += 4) {
        int r0 = rowv[i],     r1 = rowv[i + 1], r2 = rowv[i + 2], r3 = rowv[i + 3];
        float m0 = nrmv[i],   m1 = nrmv[i + 1], m2 = nrmv[i + 2], m3 = nrmv[i + 3];
        float4 v0 = *(const float4*)(x + toff + (size_t)r0 * 16);
        float4 v1 = *(const float4*)(x + toff + (size_t)r1 * 16);
        float4 v2 = *(const float4*)(x + toff + (size_t)r2 * 16);
        float4 v3 = *(const float4*)(x + toff + (size_t)r3 * 16);
        acc.x += m0 * v0.x; acc.y += m0 * v0.y; acc.z += m0 * v0.z; acc.w += m0 * v0.w;
        acc.x += m1 * v1.x; acc.y += m1 * v1.y; acc.z += m1 * v1.z; acc.w += m1 * v1.w;
        acc.x += m2 * v2.x; acc.y += m2 * v2.y; acc.z += m2 * v2.z; acc.w += m2 * v2.w;
        acc.x += m3 * v3.x; acc.y += m3 * v3.y; acc.z += m3 * v3.z; acc.w += m3 * v3.w;
        sacc += m0 + m1 + m2 + m3;
    }
    for (; i < e; i++) {
        int r0 = rowv[i];
        float m0 = nrmv[i];
        float4 v0 = *(const float4*)(x + toff + (size_t)r0 * 16);
        acc.x += m0 * v0.x; acc.y += m0 * v0.y; acc.z += m0 * v0.z; acc.w += m0 * v0.w;
        sacc += m0;
    }
    float d = dinv[n], d2 = d * d;
    float4 vs = *(const float4*)(x + toff + (size_t)n * 16);
    acc.x += d2 * vs.x; acc.y += d2 * vs.y; acc.z += d2 * vs.z; acc.w += d2 * vs.w;
    if (lane == 0) snorm[n] = sacc + d2;

    ushort4 hv, lv;
    hv.x = f2bf(acc.x); lv.x = f2bf(acc.x - bf2f(hv.x));
    hv.y = f2bf(acc.y); lv.y = f2bf(acc.y - bf2f(hv.y));
    hv.z = f2bf(acc.z); lv.z = f2bf(acc.z - bf2f(hv.z));
    hv.w = f2bf(acc.w); lv.w = f2bf(acc.w - bf2f(hv.w));
    size_t ao = (size_t)n * 256 + t * 16 + f4 * 4;
    *(ushort4*)(aggh + ao) = hv;
    *(ushort4*)(aggl + ao) = lv;
}

// MFMA GRU v3 (validated round 5): block = 64 nodes, 4 waves.
__global__ __launch_bounds__(256) void k_gru3(const ushort* __restrict__ aggh,
                                              const ushort* __restrict__ aggl,
                                              const float* __restrict__ snorm,
                                              const ushort* __restrict__ wfh,
                                              const ushort* __restrict__ wfl,
                                              const float* __restrict__ biasA,
                                              const float* __restrict__ biasB,
                                              float* __restrict__ emb) {
    __shared__ ushort sWh[36 * 64 * 8];
    __shared__ ushort sHi[64][68];
    __shared__ ushort sLo[64][68];
    int tid = threadIdx.x;
    int w = tid >> 6, l = tid & 63;
    int lg = l >> 4, lr = l & 15;
    int base = blockIdx.x * 64;
    int j = w * 16 + lr;

    for (int i = tid; i < 2304; i += 256)
        ((uint4*)sWh)[i] = ((const uint4*)wfh)[i];
    for (int i = tid; i < 64 * 68; i += 256) {
        ((ushort*)sHi)[i] = 0;
        ((ushort*)sLo)[i] = 0;
    }

    float bA[4], bB[4];
    #pragma unroll
    for (int i = 0; i < 4; i++) {
        bA[i] = biasA[i * 64 + j];
        bB[i] = biasB[i * 64 + j];
    }
    float snr[4][4], hold[4][4];
    #pragma unroll
    for (int tl = 0; tl < 4; tl++)
        #pragma unroll
        for (int q = 0; q < 4; q++) {
            int n = base + tl * 16 + lg * 4 + q;
            snr[tl][q] = snorm[min(n, NN - 1)];
            hold[tl][q] = 0.f;
        }
    int nA[4];
    #pragma unroll
    for (int tl = 0; tl < 4; tl++) nA[tl] = min(base + tl * 16 + lr, NN - 1);

    __syncthreads();

    #pragma unroll 1
    for (int t = 0; t < TT; t++) {
        short8 bh[9], bl[9];
        #pragma unroll
        for (int c = 0; c < 9; c++) {
            int offs = ((c * 4 + w) * 64 + l) * 8;
            bh[c] = *(const short8*)(sWh + offs);
            bl[c] = *(const short8*)(wfl + offs);
        }
        f32x4 acc[4][4];
        #pragma unroll
        for (int i = 0; i < 4; i++)
            #pragma unroll
            for (int tl = 0; tl < 4; tl++)
                #pragma unroll
                for (int q = 0; q < 4; q++)
                    acc[i][tl][q] = bA[i] + snr[tl][q] * bB[i];

        #pragma unroll
        for (int tl = 0; tl < 4; tl++) {
            int nd = tl * 16 + lr;
            const ushort* ph = &sHi[nd][lg * 8];
            const ushort* pl = &sLo[nd][lg * 8];
            short8 Ah0 = ld8u(ph);
            short8 Ah1 = ld8u(ph + 32);
            short8 Al0 = ld8u(pl);
            short8 Al1 = ld8u(pl + 32);
            short8 Ah2 = {0,0,0,0,0,0,0,0};
            short8 Al2 = {0,0,0,0,0,0,0,0};
            if (lg < 2) {
                size_t ao = (size_t)nA[tl] * 256 + t * 16 + lg * 8;
                Ah2 = *(const short8*)(aggh + ao);
                Al2 = *(const short8*)(aggl + ao);
            }
            acc[0][tl] = mfma3(Ah0, Al0, bh[0], bl[0], acc[0][tl]);
            acc[0][tl] = mfma3(Ah1, Al1, bh[1], bl[1], acc[0][tl]);
            acc[0][tl] = mfma3(Ah2, Al2, bh[2], bl[2], acc[0][tl]);
            acc[1][tl] = mfma3(Ah0, Al0, bh[3], bl[3], acc[1][tl]);
            acc[1][tl] = mfma3(Ah1, Al1, bh[4], bl[4], acc[1][tl]);
            acc[1][tl] = mfma3(Ah2, Al2, bh[5], bl[5], acc[1][tl]);
            acc[2][tl] = mfma3(Ah0, Al0, bh[6], bl[6], acc[2][tl]);
            acc[2][tl] = mfma3(Ah1, Al1, bh[7], bl[7], acc[2][tl]);
            acc[3][tl] = mfma3(Ah2, Al2, bh[8], bl[8], acc[3][tl]);
        }
        __syncthreads();

        #pragma unroll
        for (int tl = 0; tl < 4; tl++)
            #pragma unroll
            for (int q = 0; q < 4; q++) {
                float r = 1.f / (1.f + __expf(-acc[0][tl][q]));
                float z = 1.f / (1.f + __expf(-acc[1][tl][q]));
                float a = acc[3][tl][q] + r * acc[2][tl][q];
                a = fminf(fmaxf(a, -15.f), 15.f);
                float e2 = __expf(2.f * a);
                float nnv = (e2 - 1.f) / (e2 + 1.f);
                float hv = (1.f - z) * nnv + z * hold[tl][q];
                hold[tl][q] = hv;
                uint b = __float_as_uint(hv);
                uint hi = b & 0xFFFF0000u;
                float lo = hv - __uint_as_float(hi);
                int nd = tl * 16 + lg * 4 + q;
                sHi[nd][j] = (ushort)(hi >> 16);
                sLo[nd][j] = (ushort)(__float_as_uint(lo) >> 16);
            }
        __syncthreads();
    }

    #pragma unroll
    for (int tl = 0; tl < 4; tl++)
        #pragma unroll
        for (int q = 0; q < 4; q++) {
            int n = base + tl * 16 + lg * 4 + q;
            if (n < NN) emb[(size_t)n * 64 + j] = hold[tl][q];
        }
}

// Convert emb (N*64 = 3.2M) to bf16 hi/lo.
__global__ __launch_bounds__(256) void k_cvt(const float* __restrict__ emb,
                                             ushort* __restrict__ embh,
                                             ushort* __restrict__ embl) {
    int i = blockIdx.x * 256 + threadIdx.x;
    if (i >= NN * 64) return;
    float v = emb[i];
    ushort hb = f2bf(v);
    embh[i] = hb;
    embl[i] = f2bf(v - bf2f(hb));
}

// Edge MLP via MFMA, CSR-ordered (dst-locality), weights-hi staged in LDS,
// edge_attr handled as exact-f32 VALU epilogue term. No flow atomics:
// predv (CSR order) is segment-summed in k_node.
__global__ __launch_bounds__(256) void k_edge(const ushort* __restrict__ embh,
                                              const ushort* __restrict__ embl,
                                              const float* __restrict__ ea,
                                              const ushort* __restrict__ weh,
                                              const ushort* __restrict__ wel,
                                              const float* __restrict__ w1ea,
                                              const float2* __restrict__ b1w2,
                                              const int* __restrict__ rowv,
                                              const int* __restrict__ colv,
                                              const int* __restrict__ eidv,
                                              const float* __restrict__ e2b,
                                              float* __restrict__ pred_edge,
                                              float* __restrict__ predv) {
    __shared__ ushort sW[16384];   // 32 KB: e1W-hi frags [nt][ks][64][8]
    int tid = threadIdx.x;
    for (int i = tid; i < 2048; i += 256)
        ((uint4*)sW)[i] = ((const uint4*)weh)[i];

    int w = tid >> 6, l = tid & 63;
    int lg = l >> 4, lr = l & 15;
    int pbase = (blockIdx.x * 4 + w) * 32;

    // A-fragments from CSR slots (col-sorted -> emb[col] is cache-hot)
    short8 Ah[2][4], Al[2][4];
    #pragma unroll
    for (int s = 0; s < 2; s++) {
        int p = pbase + s * 16 + lr;
        int r = rowv[p], c = colv[p];
        #pragma unroll
        for (int ks = 0; ks < 4; ks++) {
            int src = (ks < 2) ? r : c;
            int kk = (ks & 1) * 32 + lg * 8;
            Ah[s][ks] = *(const short8*)(embh + (size_t)src * 64 + kk);
            Al[s][ks] = *(const short8*)(embl + (size_t)src * 64 + kk);
        }
    }
    // edge_attr for this lane's 8 output edges (s, q)
    float4 eav[2][4];
    #pragma unroll
    for (int s = 0; s < 2; s++)
        #pragma unroll
        for (int q = 0; q < 4; q++) {
            int p = pbase + s * 16 + lg * 4 + q;
            eav[s][q] = *(const float4*)(ea + (size_t)eidv[p] * 4);
        }
    __syncthreads();

    float esum[2][4];
    #pragma unroll
    for (int s = 0; s < 2; s++)
        #pragma unroll
        for (int q = 0; q < 4; q++) esum[s][q] = 0.f;

    #pragma unroll 1
    for (int nt = 0; nt < 8; nt++) {
        f32x4 acc[2] = {{0.f, 0.f, 0.f, 0.f}, {0.f, 0.f, 0.f, 0.f}};
        #pragma unroll
        for (int ks = 0; ks < 4; ks++) {
            int offs = ((nt * 4 + ks) * 64 + l) * 8;
            short8 bh = ld8u(sW + offs);
            short8 bl = *(const short8*)(wel + offs);
            acc[0] = mfma3(Ah[0][ks], Al[0][ks], bh, bl, acc[0]);
            acc[1] = mfma3(Ah[1][ks], Al[1][ks], bh, bl, acc[1]);
        }
        int h = nt * 16 + lr;
        float2 bw = b1w2[h];
        float4 wv = *(const float4*)(w1ea + h * 4);
        #pragma unroll
        for (int s = 0; s < 2; s++)
            #pragma unroll
            for (int q = 0; q < 4; q++) {
                float pre = acc[s][q] + bw.x
                          + wv.x * eav[s][q].x + wv.y * eav[s][q].y
                          + wv.z * eav[s][q].z + wv.w * eav[s][q].w;
                esum[s][q] += fmaxf(pre, 0.f) * bw.y;
            }
    }
    for (int m = 1; m < 16; m <<= 1)
        #pragma unroll
        for (int s = 0; s < 2; s++)
            #pragma unroll
            for (int q = 0; q < 4; q++)
                esum[s][q] += __shfl_xor(esum[s][q], m, 64);
    if (lr == 0) {
        float eb = e2b[0];
        #pragma unroll
        for (int s = 0; s < 2; s++)
            #pragma unroll
            for (int q = 0; q < 4; q++) {
                int p = pbase + s * 16 + lg * 4 + q;
                float pv = esum[s][q] + eb;
                predv[p] = pv;
                pred_edge[eidv[p]] = pv;
            }
    }
}

// Node MLP + flow segment-sum (no atomics): one wave per node.
__global__ __launch_bounds__(256) void k_node(const float* __restrict__ emb,
                                              const float* __restrict__ predv,
                                              const int* __restrict__ off,
                                              const float* __restrict__ p1W,
                                              const float* __restrict__ p1b,
                                              const float* __restrict__ p2W,
                                              const float* __restrict__ p2b,
                                              float* __restrict__ out) {
    int w = threadIdx.x >> 6, j = threadIdx.x & 63;
    int n = blockIdx.x * 4 + w;
    if (n >= NN) return;
    int s = off[n], e = off[n + 1];
    float fsum = 0.f;
    for (int i = s + j; i < e; i += 64) fsum += predv[i];
    for (int m = 1; m < 64; m <<= 1) fsum += __shfl_xor(fsum, m, 64);
    const float* wrow = p1W + j * 65;
    const float* ev = emb + (size_t)n * 64;
    float acc = p1b[j];
    for (int f = 0; f < 64; f++) acc += wrow[f] * ev[f];
    acc += wrow[64] * fsum;
    float val = p2W[j] * fmaxf(acc, 0.f);
    for (int m = 1; m < 64; m <<= 1) val += __shfl_xor(val, m, 64);
    if (j == 0) out[n] = val + p2b[0];
}

extern "C" void kernel_launch(void* const* d_in, const int* in_sizes, int n_in,
                              void* d_out, int out_size, void* d_ws, size_t ws_size,
                              hipStream_t stream) {
    (void)in_sizes; (void)n_in; (void)out_size; (void)ws_size;
    const float* x    = (const float*)d_in[0];
    const float* ea   = (const float*)d_in[1];
    const float* gcnW = (const float*)d_in[2];
    const float* gcnb = (const float*)d_in[3];
    const float* Wih  = (const float*)d_in[4];
    const float* Whh  = (const float*)d_in[5];
    const float* bih  = (const float*)d_in[6];
    const float* bhh  = (const float*)d_in[7];
    const float* e1W  = (const float*)d_in[8];
    const float* e1b  = (const float*)d_in[9];
    const float* e2W  = (const float*)d_in[10];
    const float* e2b  = (const float*)d_in[11];
    const float* p1W  = (const float*)d_in[12];
    const float* p1b  = (const float*)d_in[13];
    const float* p2W  = (const float*)d_in[14];
    const float* p2b  = (const float*)d_in[15];
    const int*   ei   = (const int*)d_in[16];

    char* ws = (char*)d_ws;
    float*  dinv  = (float*)(ws + WS_DINV);
    float*  snorm = (float*)(ws + WS_SNORM);
    float*  wc    = (float*)(ws + WS_WC);
    float*  wb    = (float*)(ws + WS_WB);
    float*  w1ea  = (float*)(ws + WS_W1EA);
    float2* b1w2  = (float2*)(ws + WS_B1W2);
    float*  biasA = (float*)(ws + WS_BA);
    float*  biasB = (float*)(ws + WS_BB);
    float*  emb   = (float*)(ws + WS_EMB);
    int*    off   = (int*)(ws + WS_OFF);
    int*    cur   = (int*)(ws + WS_CUR);
    int*    rowv  = (int*)(ws + WS_ROWV);
    int*    colv  = (int*)(ws + WS_COLV);
    int*    eidv  = (int*)(ws + WS_EIDV);
    float*  nrmv  = (float*)(ws + WS_NRMV);
    ushort* wfh   = (ushort*)(ws + WS_WFH);
    ushort* wfl   = (ushort*)(ws + WS_WFL);
    ushort* weh   = (ushort*)(ws + WS_WEH);
    ushort* wel   = (ushort*)(ws + WS_WEL);
    ushort* aggh  = (ushort*)(ws + WS_AGGH);
    ushort* aggl  = (ushort*)(ws + WS_AGGL);
    float*  predv = (float*)(ws + WS_PREDV);
    ushort* embh  = (ushort*)(ws + WS_EMBH);
    ushort* embl  = (ushort*)(ws + WS_EMBL);

    float* pred_node = (float*)d_out;
    float* pred_edge = (float*)d_out + NN;

    k_init<<<(NN + 255) / 256, 256, 0, stream>>>(dinv);
    k_deg<<<(EE + 255) / 256, 256, 0, stream>>>(ei, dinv);
    k_scan<<<1, 1024, 0, stream>>>(dinv, off, cur);
    k_dinv<<<(NN + 255) / 256, 256, 0, stream>>>(dinv);
    k_prep<<<13, 256, 0, stream>>>(Wih, gcnW, gcnb, wc, wb);
    k_prep3<<<10, 256, 0, stream>>>(Whh, wc, wb, bih, bhh, wfh, wfl, biasA, biasB);
    k_prepw<<<67, 256, 0, stream>>>(e1W, e1b, e2W, weh, wel, w1ea, b1w2);
    k_fill<<<(EE + 255) / 256, 256, 0, stream>>>(ei, dinv, cur, rowv, colv, eidv, nrmv);
    k_gather<<<(NN + 3) / 4, 256, 0, stream>>>(x, dinv, off, rowv, nrmv, aggh, aggl, snorm);
    k_gru3<<<(NN + 63) / 64, 256, 0, stream>>>(aggh, aggl, snorm, wfh, wfl, biasA, biasB, emb);
    k_cvt<<<(NN * 64 + 255) / 256, 256, 0, stream>>>(emb, embh, embl);
    k_edge<<<EE / 128, 256, 0, stream>>>(embh, embl, ea, weh, wel, w1ea, b1w2,
                                         rowv, colv, eidv, e2b, pred_edge, predv);
    k_node<<<(NN + 3) / 4, 256, 0, stream>>>(emb, predv, off, p1W, p1b, p2W, p2b, pred_node);
}